// Round 1
// baseline (556.900 us; speedup 1.0000x reference)
//
#include <hip/hip_runtime.h>

// GraphSAGE 2-layer, sum aggregation.
// N=100000 nodes, E=1600000 edges, dims 32 -> 64 -> 32, fp32.
//
// Key identity: segment_sum(h[src]) @ W^T == segment_sum((h @ W^T)[src]),
// so layer-2 aggregation runs at d=32 (on g = h@W_l_out^T) instead of d=64.
//
// ws layout (floats): agg1[N*32] | g[N*32] | agg2[N*32]  (38.4 MB)
// f (= h@W_r_out^T + b_out) is written straight into d_out; final kernel adds agg2.

#define BLK 256

__global__ void scatter_add32(const float* __restrict__ feat,
                              const int* __restrict__ ei,
                              float* __restrict__ agg, int nE) {
  int t = blockIdx.x * blockDim.x + threadIdx.x;
  int e = t >> 5;
  if (e >= nE) return;
  int k = t & 31;
  int s = ei[e];        // src row
  int d = ei[nE + e];   // dst row
  atomicAdd(&agg[d * 32 + k], feat[s * 32 + k]);
}

__global__ __launch_bounds__(256) void fused_dense(
    const float* __restrict__ x, const float* __restrict__ agg1,
    const float* __restrict__ Wl_in, const float* __restrict__ bl_in,
    const float* __restrict__ Wr_in,
    const float* __restrict__ Wl_out, const float* __restrict__ bl_out,
    const float* __restrict__ Wr_out,
    float* __restrict__ g, float* __restrict__ f, int N) {
  // weights stored TRANSPOSED in LDS: lane-d/lane-j indexes the fast dim ->
  // 2-way bank aliasing only (free on gfx950).
  __shared__ float sWl_in[32 * 64];   // [k][d]
  __shared__ float sWr_in[32 * 64];   // [k][d]
  __shared__ float sWl_out[64 * 32];  // [k][j]
  __shared__ float sWr_out[64 * 32];  // [k][j]
  __shared__ float sb_in[64];
  __shared__ float sb_out[32];
  __shared__ float sx[4][32];
  __shared__ float sa[4][32];
  __shared__ float sh[4][64];

  const int t = threadIdx.x;
  for (int idx = t; idx < 2048; idx += 256) {
    int d = idx >> 5, k = idx & 31;       // W_*_in is [64][32] row-major
    sWl_in[k * 64 + d] = Wl_in[idx];
    sWr_in[k * 64 + d] = Wr_in[idx];
    int j = idx >> 6, kk = idx & 63;      // W_*_out is [32][64] row-major
    sWl_out[kk * 32 + j] = Wl_out[idx];
    sWr_out[kk * 32 + j] = Wr_out[idx];
  }
  if (t < 64) sb_in[t] = bl_in[t];
  if (t < 32) sb_out[t] = bl_out[t];
  __syncthreads();

  const int ngroups = (N + 3) >> 2;
  for (int grp = blockIdx.x; grp < ngroups; grp += gridDim.x) {
    const int base = grp << 2;
    {  // load 4 nodes' x and agg1 rows (one float/thread, coalesced per row)
      int n = t >> 5, k = t & 31;
      int nn = n & 3;
      int node = base + nn;
      if (node < N) {
        if (n < 4) sx[nn][k] = x[(size_t)node * 32 + k];
        else       sa[nn][k] = agg1[(size_t)node * 32 + k];
      }
    }
    __syncthreads();
    {  // stage 1: h[n][d] = relu(b_in[d] + sum_k a*Wl + x*Wr)
      int n = t >> 6, d = t & 63;
      float acc = sb_in[d];
#pragma unroll
      for (int k = 0; k < 32; ++k)
        acc += sa[n][k] * sWl_in[k * 64 + d] + sx[n][k] * sWr_in[k * 64 + d];
      sh[n][d] = fmaxf(acc, 0.f);
    }
    __syncthreads();
    {  // stage 2: g[n][j] = h.Wl_out ; f[n][j] = h.Wr_out + b_out
      int n = t >> 6, c = t & 63;
      int j = c & 31;
      float acc;
      if (c < 32) {
        acc = 0.f;
#pragma unroll
        for (int k = 0; k < 64; ++k) acc += sh[n][k] * sWl_out[k * 32 + j];
      } else {
        acc = sb_out[j];
#pragma unroll
        for (int k = 0; k < 64; ++k) acc += sh[n][k] * sWr_out[k * 32 + j];
      }
      int node = base + n;
      if (node < N) {
        if (c < 32) g[(size_t)node * 32 + j] = acc;
        else        f[(size_t)node * 32 + j] = acc;
      }
    }
    __syncthreads();
  }
}

__global__ void final_add(float* __restrict__ out, const float* __restrict__ agg2, int n) {
  int i = blockIdx.x * blockDim.x + threadIdx.x;
  if (i < n) out[i] += agg2[i];
}

extern "C" void kernel_launch(void* const* d_in, const int* in_sizes, int n_in,
                              void* d_out, int out_size, void* d_ws, size_t ws_size,
                              hipStream_t stream) {
  const float* x      = (const float*)d_in[0];
  const int*   ei     = (const int*)d_in[1];
  const float* Wl_in  = (const float*)d_in[2];
  const float* bl_in  = (const float*)d_in[3];
  const float* Wr_in  = (const float*)d_in[4];
  const float* Wl_out = (const float*)d_in[5];
  const float* bl_out = (const float*)d_in[6];
  const float* Wr_out = (const float*)d_in[7];
  float* out = (float*)d_out;

  const int N = in_sizes[0] / 32;
  const int E = in_sizes[1] / 2;

  float* ws   = (float*)d_ws;
  float* agg1 = ws;
  float* g    = ws + (size_t)N * 32;
  float* agg2 = ws + (size_t)N * 64;

  hipMemsetAsync(agg1, 0, (size_t)N * 32 * sizeof(float), stream);
  hipMemsetAsync(agg2, 0, (size_t)N * 32 * sizeof(float), stream);

  const int sthreads = E * 32;
  const int sblocks  = (sthreads + BLK - 1) / BLK;

  scatter_add32<<<sblocks, BLK, 0, stream>>>(x, ei, agg1, E);
  fused_dense<<<1024, BLK, 0, stream>>>(x, agg1, Wl_in, bl_in, Wr_in,
                                        Wl_out, bl_out, Wr_out, g, out, N);
  scatter_add32<<<sblocks, BLK, 0, stream>>>(g, ei, agg2, E);
  final_add<<<(N * 32 + BLK - 1) / BLK, BLK, 0, stream>>>(out, agg2, N * 32);
}

// Round 2
// 472.375 us; speedup vs baseline: 1.1789x; 1.1789x over previous
//
#include <hip/hip_runtime.h>

// GraphSAGE 2-layer, sum aggregation. N=100000, E=1600000, 32 -> 64 -> 32, fp32.
//
// R2: replace atomic scatter (L2 atomic-rate bound, 301G/s measured ceiling)
// with CSR-by-dst build + gather aggregation (plain writes).
// Identity: segment_sum(h[src]) @ W^T == segment_sum((h @ W_l_out^T)[src]),
// so layer-2 aggregation runs at d=32 on g = h@W_l_out^T.
//
// ws layout: agg1[N*32]f | g[N*32]f | offsets[N+1]i | cursor[N]i | bsum[nb]i |
//            boff[nb]i | csr_src[E]i

#define BLK 256

// ---------- CSR build ----------

__global__ void hist_deg(const int* __restrict__ ei, int* __restrict__ deg, int E) {
  int e = blockIdx.x * blockDim.x + threadIdx.x;
  if (e < E) atomicAdd(&deg[ei[E + e]], 1);
}

__global__ void block_sum(const int* __restrict__ deg, int* __restrict__ bsum, int n) {
  int i = blockIdx.x * 256 + threadIdx.x;
  int v = (i < n) ? deg[i] : 0;
#pragma unroll
  for (int off = 32; off; off >>= 1) v += __shfl_down(v, off);
  __shared__ int wtot[4];
  if ((threadIdx.x & 63) == 0) wtot[threadIdx.x >> 6] = v;
  __syncthreads();
  if (threadIdx.x == 0) bsum[blockIdx.x] = wtot[0] + wtot[1] + wtot[2] + wtot[3];
}

// single block of 64 threads: exclusive scan of bsum[nb] -> boff[nb]
__global__ void scan_tops(const int* __restrict__ bsum, int* __restrict__ boff, int nb) {
  int lane = threadIdx.x;
  int carry = 0;
  for (int base = 0; base < nb; base += 64) {
    int i = base + lane;
    int v = (i < nb) ? bsum[i] : 0;
    int incl = v;
#pragma unroll
    for (int off = 1; off < 64; off <<= 1) {
      int nv = __shfl_up(incl, off);
      if (lane >= off) incl += nv;
    }
    if (i < nb) boff[i] = carry + incl - v;
    carry += __shfl(incl, 63);
  }
}

__global__ void scan_block(const int* __restrict__ deg, const int* __restrict__ boff,
                           int* __restrict__ offsets, int* __restrict__ cursor, int n) {
  int i = blockIdx.x * 256 + threadIdx.x;
  int v = (i < n) ? deg[i] : 0;
  int lane = threadIdx.x & 63, wid = threadIdx.x >> 6;
  int incl = v;
#pragma unroll
  for (int off = 1; off < 64; off <<= 1) {
    int nv = __shfl_up(incl, off);
    if (lane >= off) incl += nv;
  }
  __shared__ int wtot[4];
  if (lane == 63) wtot[wid] = incl;
  __syncthreads();
  int carry = 0;
  for (int w = 0; w < wid; ++w) carry += wtot[w];
  int excl = boff[blockIdx.x] + carry + incl - v;
  if (i < n) {
    offsets[i] = excl;
    if (i < n - 1) cursor[i] = excl;
  }
}

__global__ void fill_csr(const int* __restrict__ ei, int* __restrict__ cursor,
                         int* __restrict__ csr_src, int E) {
  int e = blockIdx.x * blockDim.x + threadIdx.x;
  if (e < E) {
    int d = ei[E + e];
    int pos = atomicAdd(&cursor[d], 1);
    csr_src[pos] = ei[e];
  }
}

// ---------- gather aggregation ----------
// 8 nodes per 256-thread block; 32 lanes/node; within the 32:
// q = lane>>3 picks one of 4 neighbors in flight, c = lane&7 picks float4 chunk.
__global__ void gather_agg(const float* __restrict__ feat, const int* __restrict__ offsets,
                           const int* __restrict__ csr, float* __restrict__ outp,
                           int accumulate, int N) {
  int node = blockIdx.x * 8 + (threadIdx.x >> 5);
  if (node >= N) return;
  int lane = threadIdx.x & 31;
  int q = lane >> 3, c = lane & 7;
  int beg = offsets[node], end = offsets[node + 1];
  float4 acc = make_float4(0.f, 0.f, 0.f, 0.f);
  for (int p = beg + q; p < end; p += 4) {
    int src = csr[p];
    float4 v = ((const float4*)(feat + (size_t)src * 32))[c];
    acc.x += v.x; acc.y += v.y; acc.z += v.z; acc.w += v.w;
  }
#pragma unroll
  for (int off = 8; off <= 16; off <<= 1) {
    acc.x += __shfl_xor(acc.x, off);
    acc.y += __shfl_xor(acc.y, off);
    acc.z += __shfl_xor(acc.z, off);
    acc.w += __shfl_xor(acc.w, off);
  }
  if (q == 0) {
    float4* o = (float4*)(outp + (size_t)node * 32) + c;
    if (accumulate) {
      float4 prev = *o;
      acc.x += prev.x; acc.y += prev.y; acc.z += prev.z; acc.w += prev.w;
    }
    *o = acc;
  }
}

// ---------- fused dense: one thread per node ----------
// weights indexed at wave-uniform addresses -> scalar loads + SGPR-operand fma.
__global__ __launch_bounds__(256) void dense_fused(
    const float* __restrict__ x, const float* __restrict__ agg1,
    const float* __restrict__ Wl_in, const float* __restrict__ bl_in,
    const float* __restrict__ Wr_in, const float* __restrict__ Wl_out,
    const float* __restrict__ bl_out, const float* __restrict__ Wr_out,
    float* __restrict__ g, float* __restrict__ f, int N) {
  int node = blockIdx.x * blockDim.x + threadIdx.x;
  if (node >= N) return;
  float xv[32], av[32];
  const float4* xr = (const float4*)(x + (size_t)node * 32);
  const float4* ar = (const float4*)(agg1 + (size_t)node * 32);
#pragma unroll
  for (int cc = 0; cc < 8; ++cc) {
    float4 t = xr[cc]; xv[4 * cc] = t.x; xv[4 * cc + 1] = t.y; xv[4 * cc + 2] = t.z; xv[4 * cc + 3] = t.w;
    float4 u = ar[cc]; av[4 * cc] = u.x; av[4 * cc + 1] = u.y; av[4 * cc + 2] = u.z; av[4 * cc + 3] = u.w;
  }
  float h[64];
  for (int d = 0; d < 64; ++d) {
    float acc = bl_in[d];
#pragma unroll
    for (int k = 0; k < 32; ++k)
      acc += av[k] * Wl_in[d * 32 + k] + xv[k] * Wr_in[d * 32 + k];
    h[d] = fmaxf(acc, 0.f);
  }
  float gv[32], fv[32];
  for (int j = 0; j < 32; ++j) {
    float a0 = 0.f, a1 = bl_out[j];
#pragma unroll
    for (int k = 0; k < 64; ++k) {
      a0 += h[k] * Wl_out[j * 64 + k];
      a1 += h[k] * Wr_out[j * 64 + k];
    }
    gv[j] = a0; fv[j] = a1;
  }
  float4* go = (float4*)(g + (size_t)node * 32);
  float4* fo = (float4*)(f + (size_t)node * 32);
#pragma unroll
  for (int cc = 0; cc < 8; ++cc) {
    go[cc] = make_float4(gv[4 * cc], gv[4 * cc + 1], gv[4 * cc + 2], gv[4 * cc + 3]);
    fo[cc] = make_float4(fv[4 * cc], fv[4 * cc + 1], fv[4 * cc + 2], fv[4 * cc + 3]);
  }
}

extern "C" void kernel_launch(void* const* d_in, const int* in_sizes, int n_in,
                              void* d_out, int out_size, void* d_ws, size_t ws_size,
                              hipStream_t stream) {
  const float* x      = (const float*)d_in[0];
  const int*   ei     = (const int*)d_in[1];
  const float* Wl_in  = (const float*)d_in[2];
  const float* bl_in  = (const float*)d_in[3];
  const float* Wr_in  = (const float*)d_in[4];
  const float* Wl_out = (const float*)d_in[5];
  const float* bl_out = (const float*)d_in[6];
  const float* Wr_out = (const float*)d_in[7];
  float* out = (float*)d_out;

  const int N = in_sizes[0] / 32;
  const int E = in_sizes[1] / 2;
  const int Np1 = N + 1;
  const int nb = (Np1 + 255) / 256;  // scan blocks

  float* ws   = (float*)d_ws;
  float* agg1 = ws;                       // N*32
  float* g    = ws + (size_t)N * 32;      // N*32
  int* ip     = (int*)(ws + (size_t)N * 64);
  int* offsets = ip;            // N+1 (doubles as deg before scan)
  int* cursor  = ip + Np1;      // N
  int* bsum    = ip + Np1 + N;  // nb
  int* boff    = bsum + nb;     // nb
  int* csr_src = boff + nb;     // E
  int* deg     = offsets;       // histogram in place, then scanned

  hipMemsetAsync(deg, 0, (size_t)Np1 * sizeof(int), stream);

  hist_deg<<<(E + BLK - 1) / BLK, BLK, 0, stream>>>(ei, deg, E);
  block_sum<<<nb, 256, 0, stream>>>(deg, bsum, Np1);
  scan_tops<<<1, 64, 0, stream>>>(bsum, boff, nb);
  // NOTE: scan_block reads deg and writes offsets which alias; each thread reads
  // its deg value before any thread writes -> need separation. Use cursor as
  // temp: scan into cursor first is not enough (offsets needed too). Instead,
  // scan_block reads deg[i] once at entry; writes happen after __syncthreads
  // within the block, but cross-block no ordering. Block b writes offsets[i]
  // only for its own i range and reads only its own i range -> in-place safe.
  scan_block<<<nb, 256, 0, stream>>>(deg, boff, offsets, cursor, Np1);
  fill_csr<<<(E + BLK - 1) / BLK, BLK, 0, stream>>>(ei, cursor, csr_src, E);

  gather_agg<<<(N + 7) / 8, 256, 0, stream>>>(x, offsets, csr_src, agg1, 0, N);
  dense_fused<<<(N + 255) / 256, 256, 0, stream>>>(x, agg1, Wl_in, bl_in, Wr_in,
                                                   Wl_out, bl_out, Wr_out, g, out, N);
  gather_agg<<<(N + 7) / 8, 256, 0, stream>>>(g, offsets, csr_src, out, 1, N);
}

// Round 3
// 420.184 us; speedup vs baseline: 1.3254x; 1.1242x over previous
//
#include <hip/hip_runtime.h>

// GraphSAGE 2-layer, sum aggregation. N=100000, E=1600000, 32 -> 64 -> 32, fp32.
//
// R3: fix dense kernel scratch spills (R2: 217us, VALUBusy 0.5% -> dynamic
// array indices spilled ~192 floats/thread to scratch). New dense_reg:
// stage-2 fused into d-loop, all array indices compile-time constants,
// weights via wave-uniform s_loads, ~150 VGPR, no scratch.
//
// ws layout (floats): agg1[N*32] | g[N*32] | ints{offsets[N+1],cursor[N],
//   bsum[nb],boff[nb],csr_src[E]} | WlT_out[2048] | WrT_out[2048]

#define BLK 256

// ---------- CSR build ----------

__global__ void hist_deg(const int* __restrict__ ei, int* __restrict__ deg, int E) {
  int e = blockIdx.x * blockDim.x + threadIdx.x;
  if (e < E) atomicAdd(&deg[ei[E + e]], 1);
}

__global__ void block_sum(const int* __restrict__ deg, int* __restrict__ bsum, int n) {
  int i = blockIdx.x * 256 + threadIdx.x;
  int v = (i < n) ? deg[i] : 0;
#pragma unroll
  for (int off = 32; off; off >>= 1) v += __shfl_down(v, off);
  __shared__ int wtot[4];
  if ((threadIdx.x & 63) == 0) wtot[threadIdx.x >> 6] = v;
  __syncthreads();
  if (threadIdx.x == 0) bsum[blockIdx.x] = wtot[0] + wtot[1] + wtot[2] + wtot[3];
}

__global__ void scan_tops(const int* __restrict__ bsum, int* __restrict__ boff, int nb) {
  int lane = threadIdx.x;
  int carry = 0;
  for (int base = 0; base < nb; base += 64) {
    int i = base + lane;
    int v = (i < nb) ? bsum[i] : 0;
    int incl = v;
#pragma unroll
    for (int off = 1; off < 64; off <<= 1) {
      int nv = __shfl_up(incl, off);
      if (lane >= off) incl += nv;
    }
    if (i < nb) boff[i] = carry + incl - v;
    carry += __shfl(incl, 63);
  }
}

__global__ void scan_block(const int* __restrict__ deg, const int* __restrict__ boff,
                           int* __restrict__ offsets, int* __restrict__ cursor, int n) {
  int i = blockIdx.x * 256 + threadIdx.x;
  int v = (i < n) ? deg[i] : 0;
  int lane = threadIdx.x & 63, wid = threadIdx.x >> 6;
  int incl = v;
#pragma unroll
  for (int off = 1; off < 64; off <<= 1) {
    int nv = __shfl_up(incl, off);
    if (lane >= off) incl += nv;
  }
  __shared__ int wtot[4];
  if (lane == 63) wtot[wid] = incl;
  __syncthreads();
  int carry = 0;
  for (int w = 0; w < wid; ++w) carry += wtot[w];
  int excl = boff[blockIdx.x] + carry + incl - v;
  if (i < n) {
    offsets[i] = excl;
    if (i < n - 1) cursor[i] = excl;
  }
}

__global__ void fill_csr(const int* __restrict__ ei, int* __restrict__ cursor,
                         int* __restrict__ csr_src, int E) {
  int e = blockIdx.x * blockDim.x + threadIdx.x;
  if (e < E) {
    int d = ei[E + e];
    int pos = atomicAdd(&cursor[d], 1);
    csr_src[pos] = ei[e];
  }
}

// ---------- gather aggregation ----------
__global__ void gather_agg(const float* __restrict__ feat, const int* __restrict__ offsets,
                           const int* __restrict__ csr, float* __restrict__ outp,
                           int accumulate, int N) {
  int node = blockIdx.x * 8 + (threadIdx.x >> 5);
  if (node >= N) return;
  int lane = threadIdx.x & 31;
  int q = lane >> 3, c = lane & 7;
  int beg = offsets[node], end = offsets[node + 1];
  float4 acc = make_float4(0.f, 0.f, 0.f, 0.f);
  for (int p = beg + q; p < end; p += 4) {
    int src = csr[p];
    float4 v = ((const float4*)(feat + (size_t)src * 32))[c];
    acc.x += v.x; acc.y += v.y; acc.z += v.z; acc.w += v.w;
  }
#pragma unroll
  for (int off = 8; off <= 16; off <<= 1) {
    acc.x += __shfl_xor(acc.x, off);
    acc.y += __shfl_xor(acc.y, off);
    acc.z += __shfl_xor(acc.z, off);
    acc.w += __shfl_xor(acc.w, off);
  }
  if (q == 0) {
    float4* o = (float4*)(outp + (size_t)node * 32) + c;
    if (accumulate) {
      float4 prev = *o;
      acc.x += prev.x; acc.y += prev.y; acc.z += prev.z; acc.w += prev.w;
    }
    *o = acc;
  }
}

// ---------- transpose out-weights: W[32][64] -> WT[64][32] ----------
__global__ void transpose_w(const float* __restrict__ Wl, const float* __restrict__ Wr,
                            float* __restrict__ WlT, float* __restrict__ WrT) {
  int idx = blockIdx.x * 256 + threadIdx.x;  // idx = k*32 + j, 2048 total
  if (idx >= 2048) return;
  int j = idx & 31, k = idx >> 5;
  WlT[idx] = Wl[j * 64 + k];
  WrT[idx] = Wr[j * 64 + k];
}

// ---------- fused dense, register-resident ----------
// One thread per node. All per-thread array indices are compile-time constant
// (full unroll) -> arrays live in VGPRs (~150). Weights are wave-uniform ->
// s_load from scalar cache. Stage 2 fused into d-loop: no h[64] array.
__global__ __launch_bounds__(256) void dense_reg(
    const float* __restrict__ x, const float* __restrict__ agg1,
    const float* __restrict__ Wl_in, const float* __restrict__ bl_in,
    const float* __restrict__ Wr_in,
    const float* __restrict__ WlT_out, const float* __restrict__ bl_out,
    const float* __restrict__ WrT_out,
    float* __restrict__ g, float* __restrict__ f, int N) {
  int node = blockIdx.x * blockDim.x + threadIdx.x;
  if (node >= N) return;
  float xv[32], av[32];
  const float4* xr = (const float4*)(x + (size_t)node * 32);
  const float4* ar = (const float4*)(agg1 + (size_t)node * 32);
#pragma unroll
  for (int c = 0; c < 8; ++c) {
    float4 t = xr[c];
    xv[4*c] = t.x; xv[4*c+1] = t.y; xv[4*c+2] = t.z; xv[4*c+3] = t.w;
    float4 u = ar[c];
    av[4*c] = u.x; av[4*c+1] = u.y; av[4*c+2] = u.z; av[4*c+3] = u.w;
  }
  float gv[32], fv[32];
#pragma unroll
  for (int j = 0; j < 32; ++j) { gv[j] = 0.f; fv[j] = bl_out[j]; }

  for (int d = 0; d < 64; ++d) {
    const float* wl = Wl_in + d * 32;
    const float* wr = Wr_in + d * 32;
    float h0 = bl_in[d], h1 = 0.f, h2 = 0.f, h3 = 0.f;
#pragma unroll
    for (int k = 0; k < 32; k += 4) {
      h0 += av[k]     * wl[k]     + xv[k]     * wr[k];
      h1 += av[k + 1] * wl[k + 1] + xv[k + 1] * wr[k + 1];
      h2 += av[k + 2] * wl[k + 2] + xv[k + 2] * wr[k + 2];
      h3 += av[k + 3] * wl[k + 3] + xv[k + 3] * wr[k + 3];
    }
    float hd = fmaxf((h0 + h1) + (h2 + h3), 0.f);
    const float* wlo = WlT_out + d * 32;
    const float* wro = WrT_out + d * 32;
#pragma unroll
    for (int j = 0; j < 32; ++j) {
      gv[j] += hd * wlo[j];
      fv[j] += hd * wro[j];
    }
  }

  float4* go = (float4*)(g + (size_t)node * 32);
  float4* fo = (float4*)(f + (size_t)node * 32);
#pragma unroll
  for (int c = 0; c < 8; ++c) {
    go[c] = make_float4(gv[4*c], gv[4*c+1], gv[4*c+2], gv[4*c+3]);
    fo[c] = make_float4(fv[4*c], fv[4*c+1], fv[4*c+2], fv[4*c+3]);
  }
}

extern "C" void kernel_launch(void* const* d_in, const int* in_sizes, int n_in,
                              void* d_out, int out_size, void* d_ws, size_t ws_size,
                              hipStream_t stream) {
  const float* x      = (const float*)d_in[0];
  const int*   ei     = (const int*)d_in[1];
  const float* Wl_in  = (const float*)d_in[2];
  const float* bl_in  = (const float*)d_in[3];
  const float* Wr_in  = (const float*)d_in[4];
  const float* Wl_out = (const float*)d_in[5];
  const float* bl_out = (const float*)d_in[6];
  const float* Wr_out = (const float*)d_in[7];
  float* out = (float*)d_out;

  const int N = in_sizes[0] / 32;
  const int E = in_sizes[1] / 2;
  const int Np1 = N + 1;
  const int nb = (Np1 + 255) / 256;

  float* ws   = (float*)d_ws;
  float* agg1 = ws;                       // N*32
  float* g    = ws + (size_t)N * 32;      // N*32
  int* ip      = (int*)(ws + (size_t)N * 64);
  int* offsets = ip;            // N+1 (deg -> scanned in place)
  int* cursor  = ip + Np1;      // N
  int* bsum    = ip + Np1 + N;  // nb
  int* boff    = bsum + nb;     // nb
  int* csr_src = boff + nb;     // E
  int* deg     = offsets;
  float* WlT   = (float*)(csr_src + E);  // 2048
  float* WrT   = WlT + 2048;             // 2048

  hipMemsetAsync(deg, 0, (size_t)Np1 * sizeof(int), stream);

  transpose_w<<<8, 256, 0, stream>>>(Wl_out, Wr_out, WlT, WrT);
  hist_deg<<<(E + BLK - 1) / BLK, BLK, 0, stream>>>(ei, deg, E);
  block_sum<<<nb, 256, 0, stream>>>(deg, bsum, Np1);
  scan_tops<<<1, 64, 0, stream>>>(bsum, boff, nb);
  scan_block<<<nb, 256, 0, stream>>>(deg, boff, offsets, cursor, Np1);
  fill_csr<<<(E + BLK - 1) / BLK, BLK, 0, stream>>>(ei, cursor, csr_src, E);

  gather_agg<<<(N + 7) / 8, 256, 0, stream>>>(x, offsets, csr_src, agg1, 0, N);
  dense_reg<<<(N + 255) / 256, 256, 0, stream>>>(x, agg1, Wl_in, bl_in, Wr_in,
                                                 WlT, bl_out, WrT, g, out, N);
  gather_agg<<<(N + 7) / 8, 256, 0, stream>>>(g, offsets, csr_src, out, 1, N);
}

// Round 4
// 369.905 us; speedup vs baseline: 1.5055x; 1.1359x over previous
//
#include <hip/hip_runtime.h>

// GraphSAGE 2-layer, sum aggregation. N=100000, E=1600000, 32 -> 64 -> 32, fp32.
//
// R4: fill_csr was 143us with WRITE_SIZE=106MB -- scattered 4B writes, each
// 64B csr line dirtied across random XCDs => ~16x write amplification.
// Fix: dst-range-sliced fill. Block b handles dst slice (b&7) over edge chunk
// (b>>3); each slice's csr region (0.8MB) stays resident in one XCD's L2,
// lines fill completely before writeback. dst array read 8x (LLC-hot).
//
// ws layout (floats): agg1[N*32] | g[N*32] | ints{offsets[N+1],cursor[N],
//   bsum[nb],boff[nb],csr_src[E]} | WlT_out[2048] | WrT_out[2048]

#define BLK 256

// ---------- CSR build ----------

__global__ void hist_deg(const int* __restrict__ ei, int* __restrict__ deg, int E) {
  int e = blockIdx.x * blockDim.x + threadIdx.x;
  if (e < E) atomicAdd(&deg[ei[E + e]], 1);
}

__global__ void block_sum(const int* __restrict__ deg, int* __restrict__ bsum, int n) {
  int i = blockIdx.x * 256 + threadIdx.x;
  int v = (i < n) ? deg[i] : 0;
#pragma unroll
  for (int off = 32; off; off >>= 1) v += __shfl_down(v, off);
  __shared__ int wtot[4];
  if ((threadIdx.x & 63) == 0) wtot[threadIdx.x >> 6] = v;
  __syncthreads();
  if (threadIdx.x == 0) bsum[blockIdx.x] = wtot[0] + wtot[1] + wtot[2] + wtot[3];
}

__global__ void scan_tops(const int* __restrict__ bsum, int* __restrict__ boff, int nb) {
  int lane = threadIdx.x;
  int carry = 0;
  for (int base = 0; base < nb; base += 64) {
    int i = base + lane;
    int v = (i < nb) ? bsum[i] : 0;
    int incl = v;
#pragma unroll
    for (int off = 1; off < 64; off <<= 1) {
      int nv = __shfl_up(incl, off);
      if (lane >= off) incl += nv;
    }
    if (i < nb) boff[i] = carry + incl - v;
    carry += __shfl(incl, 63);
  }
}

__global__ void scan_block(const int* __restrict__ deg, const int* __restrict__ boff,
                           int* __restrict__ offsets, int* __restrict__ cursor, int n) {
  int i = blockIdx.x * 256 + threadIdx.x;
  int v = (i < n) ? deg[i] : 0;
  int lane = threadIdx.x & 63, wid = threadIdx.x >> 6;
  int incl = v;
#pragma unroll
  for (int off = 1; off < 64; off <<= 1) {
    int nv = __shfl_up(incl, off);
    if (lane >= off) incl += nv;
  }
  __shared__ int wtot[4];
  if (lane == 63) wtot[wid] = incl;
  __syncthreads();
  int carry = 0;
  for (int w = 0; w < wid; ++w) carry += wtot[w];
  int excl = boff[blockIdx.x] + carry + incl - v;
  if (i < n) {
    offsets[i] = excl;
    if (i < n - 1) cursor[i] = excl;
  }
}

// dst-sliced CSR fill: slice = blockIdx&7 (XCD round-robin heuristic),
// chunk = blockIdx>>3 over the edge list. Writes for one slice land in a
// 0.8MB csr region -> L2-resident, full-line writebacks.
__global__ void fill_csr_sliced(const int* __restrict__ ei, int* __restrict__ cursor,
                                int* __restrict__ csr_src, int E, int N) {
  const int slice = blockIdx.x & 7;
  const int nchunk = gridDim.x >> 3;
  const int chunk = blockIdx.x >> 3;
  const int lo = (N * slice) >> 3;
  const int hi = (N * (slice + 1)) >> 3;
  const int per = (E + nchunk - 1) / nchunk;
  const int beg = chunk * per;
  const int end = min(beg + per, E);
  for (int e = beg + (int)threadIdx.x; e < end; e += (int)blockDim.x) {
    int d = ei[E + e];
    if (d >= lo && d < hi) {
      int pos = atomicAdd(&cursor[d], 1);
      csr_src[pos] = ei[e];
    }
  }
}

// ---------- gather aggregation ----------
__global__ void gather_agg(const float* __restrict__ feat, const int* __restrict__ offsets,
                           const int* __restrict__ csr, float* __restrict__ outp,
                           int accumulate, int N) {
  int node = blockIdx.x * 8 + (threadIdx.x >> 5);
  if (node >= N) return;
  int lane = threadIdx.x & 31;
  int q = lane >> 3, c = lane & 7;
  int beg = offsets[node], end = offsets[node + 1];
  float4 acc = make_float4(0.f, 0.f, 0.f, 0.f);
  for (int p = beg + q; p < end; p += 4) {
    int src = csr[p];
    float4 v = ((const float4*)(feat + (size_t)src * 32))[c];
    acc.x += v.x; acc.y += v.y; acc.z += v.z; acc.w += v.w;
  }
#pragma unroll
  for (int off = 8; off <= 16; off <<= 1) {
    acc.x += __shfl_xor(acc.x, off);
    acc.y += __shfl_xor(acc.y, off);
    acc.z += __shfl_xor(acc.z, off);
    acc.w += __shfl_xor(acc.w, off);
  }
  if (q == 0) {
    float4* o = (float4*)(outp + (size_t)node * 32) + c;
    if (accumulate) {
      float4 prev = *o;
      acc.x += prev.x; acc.y += prev.y; acc.z += prev.z; acc.w += prev.w;
    }
    *o = acc;
  }
}

// ---------- transpose out-weights: W[32][64] -> WT[64][32] ----------
__global__ void transpose_w(const float* __restrict__ Wl, const float* __restrict__ Wr,
                            float* __restrict__ WlT, float* __restrict__ WrT) {
  int idx = blockIdx.x * 256 + threadIdx.x;  // idx = k*32 + j, 2048 total
  if (idx >= 2048) return;
  int j = idx & 31, k = idx >> 5;
  WlT[idx] = Wl[j * 64 + k];
  WrT[idx] = Wr[j * 64 + k];
}

// ---------- fused dense, register-resident ----------
__global__ __launch_bounds__(256) void dense_reg(
    const float* __restrict__ x, const float* __restrict__ agg1,
    const float* __restrict__ Wl_in, const float* __restrict__ bl_in,
    const float* __restrict__ Wr_in,
    const float* __restrict__ WlT_out, const float* __restrict__ bl_out,
    const float* __restrict__ WrT_out,
    float* __restrict__ g, float* __restrict__ f, int N) {
  int node = blockIdx.x * blockDim.x + threadIdx.x;
  if (node >= N) return;
  float xv[32], av[32];
  const float4* xr = (const float4*)(x + (size_t)node * 32);
  const float4* ar = (const float4*)(agg1 + (size_t)node * 32);
#pragma unroll
  for (int c = 0; c < 8; ++c) {
    float4 t = xr[c];
    xv[4*c] = t.x; xv[4*c+1] = t.y; xv[4*c+2] = t.z; xv[4*c+3] = t.w;
    float4 u = ar[c];
    av[4*c] = u.x; av[4*c+1] = u.y; av[4*c+2] = u.z; av[4*c+3] = u.w;
  }
  float gv[32], fv[32];
#pragma unroll
  for (int j = 0; j < 32; ++j) { gv[j] = 0.f; fv[j] = bl_out[j]; }

  for (int d = 0; d < 64; ++d) {
    const float* wl = Wl_in + d * 32;
    const float* wr = Wr_in + d * 32;
    float h0 = bl_in[d], h1 = 0.f, h2 = 0.f, h3 = 0.f;
#pragma unroll
    for (int k = 0; k < 32; k += 4) {
      h0 += av[k]     * wl[k]     + xv[k]     * wr[k];
      h1 += av[k + 1] * wl[k + 1] + xv[k + 1] * wr[k + 1];
      h2 += av[k + 2] * wl[k + 2] + xv[k + 2] * wr[k + 2];
      h3 += av[k + 3] * wl[k + 3] + xv[k + 3] * wr[k + 3];
    }
    float hd = fmaxf((h0 + h1) + (h2 + h3), 0.f);
    const float* wlo = WlT_out + d * 32;
    const float* wro = WrT_out + d * 32;
#pragma unroll
    for (int j = 0; j < 32; ++j) {
      gv[j] += hd * wlo[j];
      fv[j] += hd * wro[j];
    }
  }

  float4* go = (float4*)(g + (size_t)node * 32);
  float4* fo = (float4*)(f + (size_t)node * 32);
#pragma unroll
  for (int c = 0; c < 8; ++c) {
    go[c] = make_float4(gv[4*c], gv[4*c+1], gv[4*c+2], gv[4*c+3]);
    fo[c] = make_float4(fv[4*c], fv[4*c+1], fv[4*c+2], fv[4*c+3]);
  }
}

extern "C" void kernel_launch(void* const* d_in, const int* in_sizes, int n_in,
                              void* d_out, int out_size, void* d_ws, size_t ws_size,
                              hipStream_t stream) {
  const float* x      = (const float*)d_in[0];
  const int*   ei     = (const int*)d_in[1];
  const float* Wl_in  = (const float*)d_in[2];
  const float* bl_in  = (const float*)d_in[3];
  const float* Wr_in  = (const float*)d_in[4];
  const float* Wl_out = (const float*)d_in[5];
  const float* bl_out = (const float*)d_in[6];
  const float* Wr_out = (const float*)d_in[7];
  float* out = (float*)d_out;

  const int N = in_sizes[0] / 32;
  const int E = in_sizes[1] / 2;
  const int Np1 = N + 1;
  const int nb = (Np1 + 255) / 256;

  float* ws   = (float*)d_ws;
  float* agg1 = ws;                       // N*32
  float* g    = ws + (size_t)N * 32;      // N*32
  int* ip      = (int*)(ws + (size_t)N * 64);
  int* offsets = ip;            // N+1 (deg -> scanned in place)
  int* cursor  = ip + Np1;      // N
  int* bsum    = ip + Np1 + N;  // nb
  int* boff    = bsum + nb;     // nb
  int* csr_src = boff + nb;     // E
  int* deg     = offsets;
  float* WlT   = (float*)(csr_src + E);  // 2048
  float* WrT   = WlT + 2048;             // 2048

  hipMemsetAsync(deg, 0, (size_t)Np1 * sizeof(int), stream);

  transpose_w<<<8, 256, 0, stream>>>(Wl_out, Wr_out, WlT, WrT);
  hist_deg<<<(E + BLK - 1) / BLK, BLK, 0, stream>>>(ei, deg, E);
  block_sum<<<nb, 256, 0, stream>>>(deg, bsum, Np1);
  scan_tops<<<1, 64, 0, stream>>>(bsum, boff, nb);
  scan_block<<<nb, 256, 0, stream>>>(deg, boff, offsets, cursor, Np1);
  fill_csr_sliced<<<512, BLK, 0, stream>>>(ei, cursor, csr_src, E, N);

  gather_agg<<<(N + 7) / 8, 256, 0, stream>>>(x, offsets, csr_src, agg1, 0, N);
  dense_reg<<<(N + 255) / 256, 256, 0, stream>>>(x, agg1, Wl_in, bl_in, Wr_in,
                                                 WlT, bl_out, WrT, g, out, N);
  gather_agg<<<(N + 7) / 8, 256, 0, stream>>>(g, offsets, csr_src, out, 1, N);
}